// Round 5
// baseline (178.106 us; speedup 1.0000x reference)
//
#include <hip/hip_runtime.h>
#include <hip/hip_bf16.h>

#define NUM_SLOTS 168
#define NUM_CATS 2048
#define BATCH 512
#define SEQ 200
#define ROWS_PER_BLOCK 100   // 1024 blocks * 100 = 102,400 = BATCH*SEQ exactly
#define GATHER_BLOCKS ((BATCH * SEQ) / ROWS_PER_BLOCK)

// Native clang vector type — __builtin_nontemporal_store requires a vector of
// scalars, not HIP's HIP_vector_type class.
typedef float v4f __attribute__((ext_vector_type(4)));

// Kernel 1: row-wise softmax of the [168, 2048] matrix into workspace.
// One block (256 threads) per row; each thread owns 8 elements.
__global__ void softmax_rows_kernel(const float* __restrict__ mat,
                                    float* __restrict__ probs) {
    const int row = blockIdx.x;
    const float* r = mat + row * NUM_CATS;
    float* o = probs + row * NUM_CATS;
    const int t = threadIdx.x;

    float vals[8];
    float mx = -INFINITY;
#pragma unroll
    for (int j = 0; j < 8; ++j) {
        vals[j] = r[t + j * 256];
        mx = fmaxf(mx, vals[j]);
    }
    // wave (64-lane) butterfly max
#pragma unroll
    for (int off = 32; off >= 1; off >>= 1) mx = fmaxf(mx, __shfl_xor(mx, off));

    __shared__ float redmax[4];
    __shared__ float redsum[4];
    const int wave = t >> 6;
    if ((t & 63) == 0) redmax[wave] = mx;
    __syncthreads();
    mx = fmaxf(fmaxf(redmax[0], redmax[1]), fmaxf(redmax[2], redmax[3]));

    float sum = 0.0f;
#pragma unroll
    for (int j = 0; j < 8; ++j) {
        vals[j] = expf(vals[j] - mx);
        sum += vals[j];
    }
#pragma unroll
    for (int off = 32; off >= 1; off >>= 1) sum += __shfl_xor(sum, off);
    if ((t & 63) == 0) redsum[wave] = sum;
    __syncthreads();
    sum = redsum[0] + redsum[1] + redsum[2] + redsum[3];

    const float inv = 1.0f / sum;
#pragma unroll
    for (int j = 0; j < 8; ++j) o[t + j * 256] = vals[j] * inv;
}

// Kernel 2: gather/expand, software-pipelined 2 rows deep so the probs load
// consumed this iteration was issued 2 iterations ago. This decouples the
// in-order vmcnt chain: stores issue back-to-back without a dependent load
// draining them each row. hours[row] stays block-uniform (scalar cache).
__global__ void __launch_bounds__(256)
gather_rows_kernel(const int* __restrict__ hours,
                   const v4f* __restrict__ probs,
                   v4f* __restrict__ out) {
    const int t = threadIdx.x;                       // 0..255
    const int row0 = blockIdx.x * ROWS_PER_BLOCK;

    // prologue: prefetch rows 0 and 1
    const int h0 = hours[row0];
    const int h1 = hours[row0 + 1];
    v4f a0 = probs[(h0 << 9) + t];
    v4f b0 = probs[(h0 << 9) + t + 256];
    v4f a1 = probs[(h1 << 9) + t];
    v4f b1 = probs[(h1 << 9) + t + 256];

    for (int r = 0; r < ROWS_PER_BLOCK; ++r) {
        v4f* __restrict__ dst = out + ((size_t)(row0 + r) << 9);
        __builtin_nontemporal_store(a0, &dst[t]);
        __builtin_nontemporal_store(b0, &dst[t + 256]);
        a0 = a1; b0 = b1;
        if (r + 2 < ROWS_PER_BLOCK) {                // uniform branch
            const int h2 = hours[row0 + r + 2];      // scalar load
            a1 = probs[(h2 << 9) + t];
            b1 = probs[(h2 << 9) + t + 256];
        }
    }
}

extern "C" void kernel_launch(void* const* d_in, const int* in_sizes, int n_in,
                              void* d_out, int out_size, void* d_ws, size_t ws_size,
                              hipStream_t stream) {
    const int* inputs_hour = (const int*)d_in[0];            // [512, 200] int32
    const float* catid_time_matrix = (const float*)d_in[1];  // [168, 2048] f32
    float* out = (float*)d_out;                               // [512, 200, 2048] f32
    float* probs = (float*)d_ws;                              // 168*2048 f32 = 1.38 MB

    // Step 1: softmax (tiny)
    softmax_rows_kernel<<<NUM_SLOTS, 256, 0, stream>>>(catid_time_matrix, probs);

    // Step 2: gather/expand (write-BW-bound). 1024 blocks (4/CU), each owns an
    // 800 KB contiguous output region — fewer, longer write streams.
    gather_rows_kernel<<<GATHER_BLOCKS, 256, 0, stream>>>(
        inputs_hour, (const v4f*)probs, (v4f*)out);
}